// Round 5
// baseline (315.681 us; speedup 1.0000x reference)
//
#include <hip/hip_runtime.h>

// Viterbi decode (LinearCRF): features [B,S,L] f32, transitions [L,L] f32 -> best_path [B,S] int32
// B=512, S=1024, L=64. One wave per batch element; lane = tag j.
// Wall time == per-step dependent-chain latency x 1023 (serial recurrence, SIMDs idle).
constexpr int Bn = 512;
constexpr int Sn = 1024;
constexpr int Ln = 64;

// ---- wave64 max reduction via DPP ----
#define DPPMAX(ctrl)                                                          \
  {                                                                           \
    int _xi = __float_as_int(x);                                              \
    int _yi = __builtin_amdgcn_update_dpp(_xi, _xi, ctrl, 0xf, 0xf, false);   \
    x = fmaxf(x, __int_as_float(_yi));                                        \
  }

__device__ __forceinline__ float wave_max64(float x) {
  DPPMAX(0x121)  // row_ror:1
  DPPMAX(0x122)  // row_ror:2
  DPPMAX(0x124)  // row_ror:4
  DPPMAX(0x128)  // row_ror:8
  DPPMAX(0x142)  // row_bcast15
  DPPMAX(0x143)  // row_bcast31 -> lane 63 holds wave max
  return __int_as_float(__builtin_amdgcn_readlane(__float_as_int(x), 63));
}

__device__ __forceinline__ float rdlane(float v, int lane) {
  return __int_as_float(__builtin_amdgcn_readlane(__float_as_int(v), lane));
}

// One Viterbi step, branch-free for k<=4 candidates (covers ~all steps).
// Exact arithmetic: scores rnd(fv_i + T[i][j]); selection strict-> ascending index
// == np.argmax first-index rule; candidate set provably supersets column winners
// (margin Dspan + 0.01 >> fp slack). Slots duplicate i0 when k<4 (tie-safe).
#define CRF_STEP(T_, FEATC_)                                                     \
  do {                                                                           \
    const float M_ = wave_max64(fv);                                             \
    const float thr_ = M_ - DpE;                                                 \
    const unsigned long long cm_ = __ballot(fv >= thr_);                         \
    const int k_ = __popcll(cm_);                                                \
    const int i0_ = __ffsll((long long)cm_) - 1;                                 \
    const unsigned long long m1_ = cm_ & (cm_ - 1);                              \
    const unsigned long long m2_ = m1_ & (m1_ - 1);                              \
    const unsigned long long m3_ = m2_ & (m2_ - 1);                              \
    const int i1_ = (k_ > 1) ? (__ffsll((long long)m1_) - 1) : i0_;              \
    const int i2_ = (k_ > 2) ? (__ffsll((long long)m2_) - 1) : i0_;              \
    const int i3_ = (k_ > 3) ? (__ffsll((long long)m3_) - 1) : i0_;              \
    const float t0_ = sT[i0_ * Ln + j];                                          \
    const float t1_ = sT[i1_ * Ln + j];                                          \
    const float t2_ = sT[i2_ * Ln + j];                                          \
    const float t3_ = sT[i3_ * Ln + j];                                          \
    const float s0_ = rdlane(fv, i0_) + t0_;                                     \
    const float s1_ = rdlane(fv, i1_) + t1_;                                     \
    const float s2_ = rdlane(fv, i2_) + t2_;                                     \
    const float s3_ = rdlane(fv, i3_) + t3_;                                     \
    /* depth-2 select tree, first-index tie rule */                              \
    const bool tkA_ = s1_ > s0_;                                                 \
    const float vA_ = tkA_ ? s1_ : s0_;                                          \
    const int xA_ = tkA_ ? i1_ : i0_;                                            \
    const bool tkB_ = s3_ > s2_;                                                 \
    float vB_ = tkB_ ? s3_ : s2_;                                                \
    int xB_ = tkB_ ? i3_ : i2_;                                                  \
    bool tkF_ = vB_ > vA_;                                                       \
    float best_ = tkF_ ? vB_ : vA_;                                              \
    int bx_ = tkF_ ? xB_ : xA_;                                                  \
    if (__builtin_expect(k_ > 4, 0)) {                                           \
      /* ultra-rare: extend scan over remaining candidate bits (ascending) */    \
      unsigned long long m_ = m3_ & (m3_ - 1);                                   \
      while (m_) {                                                               \
        const int i_ = __ffsll((long long)m_) - 1;                               \
        m_ &= m_ - 1;                                                            \
        const float s_ = rdlane(fv, i_) + sT[i_ * Ln + j];                       \
        const bool tk_ = s_ > best_;                                             \
        best_ = tk_ ? s_ : best_;                                                \
        bx_ = tk_ ? i_ : bx_;                                                    \
      }                                                                          \
    }                                                                            \
    fv = (FEATC_) + best_;                                                       \
    bpb[(size_t)((T_) - 1) * Ln] = (unsigned char)bx_;                           \
    const int f0_ = __builtin_amdgcn_readfirstlane(bx_);                         \
    const unsigned cv_ = (__ballot(bx_ == f0_) == ~0ull) ? (unsigned)f0_         \
                                                         : 0xFFu;                \
    cw = cw | (cv_ << (8 * ((T_) & 3)));                                         \
    if (((T_) & 3) == 3) {                                                       \
      if (j == 0) coalw[(T_) >> 2] = cw;                                         \
      cw = 0;                                                                    \
    }                                                                            \
  } while (0)

__global__ __launch_bounds__(64) void crf_forward(
    const float* __restrict__ feat,       // [B][S][L]
    const float* __restrict__ Tm,         // [L][L]
    unsigned char* __restrict__ bp,       // [B][S-1][L] backpointers
    unsigned* __restrict__ coal,          // [B][S/4 words]: per-step istar or 0xFF bytes
    int* __restrict__ last_tag)           // [B]
{
  const int b = blockIdx.x;
  const int j = threadIdx.x;  // tag index 0..63

  __shared__ __align__(16) float sT[Ln * Ln];  // transitions row-major

  // stage T, tracking global span
  float tmx = -1e30f, tmn = 1e30f;
#pragma unroll 8
  for (int i = 0; i < Ln; ++i) {
    const float v = Tm[i * Ln + j];
    sT[i * Ln + j] = v;
    tmx = fmaxf(tmx, v);
    tmn = fminf(tmn, v);
  }
  __syncthreads();
#pragma unroll
  for (int off = 32; off >= 1; off >>= 1) {
    tmx = fmaxf(tmx, __shfl_xor(tmx, off));
    tmn = fminf(tmn, __shfl_xor(tmn, off));
  }
  // fixed margin: Dspan + 0.01 covers all fp rounding (|fv| <= ~6e3 -> 2ulp ~ 1e-3)
  const float DpE = (tmx - tmn) + 0.01f;

  const float* fb = feat + ((size_t)b * Sn) * Ln + j;
  unsigned char* bpb = bp + ((size_t)b * (Sn - 1)) * Ln + j;
  unsigned* coalw = coal + (size_t)b * (Sn / 4);

  unsigned cw = 0;

  // forward_var = features[b][0][:]; 8-deep software prefetch ring (static indices)
  float fv = fb[0];
  float pf[8];
#pragma unroll
  for (int u = 0; u < 8; ++u) pf[u] = fb[(size_t)(1 + u) * Ln];

  // ---- phase 1: t = 1 .. 1008 (126 blocks of 8); prefetch t+8 <= 1016, no clamp ----
  for (int tb = 1; tb <= Sn - 16; tb += 8) {
#pragma unroll
    for (int u = 0; u < 8; ++u) {
      const int t = tb + u;
      const float featc = pf[u];
      pf[u] = fb[(size_t)(t + 8) * Ln];
      CRF_STEP(t, featc);
    }
  }
  // After phase 1: pf[u] = feature[1009 + u].

  // ---- phase 2: t = 1009 .. 1016; refill pf[0..6] with features 1017..1023 ----
#pragma unroll
  for (int u = 0; u < 8; ++u) {
    const int t = 1009 + u;
    const float featc = pf[u];
    if (u < 7) pf[u] = fb[(size_t)(1017 + u) * Ln];
    CRF_STEP(t, featc);
  }

  // ---- phase 3: t = 1017 .. 1023 ----
#pragma unroll
  for (int u = 0; u < 7; ++u) {
    const int t = 1017 + u;
    const float featc = pf[u];
    CRF_STEP(t, featc);
  }

  // last_tag = first-index argmax of final forward_var
  const float Mf = wave_max64(fv);
  const unsigned long long mk = __ballot(fv == Mf);
  if (j == 0) last_tag[b] = __ffsll((long long)mk) - 1;
}

__global__ __launch_bounds__(256) void crf_backtrace(
    const unsigned char* __restrict__ bp, const unsigned char* __restrict__ coal,
    const int* __restrict__ last_tag, int* __restrict__ out)
{
  const int gid = blockIdx.x * blockDim.x + threadIdx.x;
  if (gid >= Bn * Sn) return;
  const int b = gid >> 10;       // / Sn
  const int t = gid & (Sn - 1);  // % Sn

  const unsigned char* cb = coal + (size_t)b * Sn;
  int tag = -1;
  int u = t;
  // walk forward to the nearest chain break (coalesced step or sequence end)
  while (u < Sn - 1) {
    const unsigned char c = cb[u + 1];
    if (c != 0xFF) { tag = c; break; }  // path[u] = istar of step u+1
    ++u;
  }
  if (u == Sn - 1) tag = last_tag[b];
  // walk back through non-coalesced steps applying stored backpointers
  const unsigned char* bpb = bp + (size_t)b * (Sn - 1) * Ln;
  for (; u > t; --u) tag = bpb[(size_t)(u - 1) * Ln + tag];
  out[gid] = tag;
}

extern "C" void kernel_launch(void* const* d_in, const int* in_sizes, int n_in,
                              void* d_out, int out_size, void* d_ws, size_t ws_size,
                              hipStream_t stream) {
  const float* feat = (const float*)d_in[0];
  const float* Tm = (const float*)d_in[1];

  // workspace layout: bp | coal | last_tag   (~34 MB total)
  unsigned char* bp = (unsigned char*)d_ws;
  const size_t bp_sz = (size_t)Bn * (Sn - 1) * Ln;  // 33,521,664 (word-aligned)
  unsigned char* coal = bp + bp_sz;
  const size_t coal_sz = (size_t)Bn * Sn;           // 524,288
  int* last_tag = (int*)(coal + coal_sz);

  int* out = (int*)d_out;

  crf_forward<<<Bn, 64, 0, stream>>>(feat, Tm, bp, (unsigned*)coal, last_tag);
  const int total = Bn * Sn;
  crf_backtrace<<<(total + 255) / 256, 256, 0, stream>>>(bp, coal, last_tag, out);
}

// Round 7
// 220.784 us; speedup vs baseline: 1.4298x; 1.4298x over previous
//
#include <hip/hip_runtime.h>

// Viterbi decode (LinearCRF): features [B,S,L] f32, transitions [L,L] f32 -> best_path [B,S] int32
// B=512, S=1024, L=64. One wave per batch element; lane = tag j.
// Serial 1023-step recurrence; lone wave pays ~3.5 cyc/instr -> minimize instrs/step.
constexpr int Bn = 512;
constexpr int Sn = 1024;
constexpr int Ln = 64;

// ---- wave64 max reduction via DPP ----
#define DPPMAX(ctrl)                                                          \
  {                                                                           \
    int _xi = __float_as_int(x);                                              \
    int _yi = __builtin_amdgcn_update_dpp(_xi, _xi, ctrl, 0xf, 0xf, false);   \
    x = fmaxf(x, __int_as_float(_yi));                                        \
  }

__device__ __forceinline__ float wave_max64(float x) {
  DPPMAX(0x121)  // row_ror:1
  DPPMAX(0x122)  // row_ror:2
  DPPMAX(0x124)  // row_ror:4
  DPPMAX(0x128)  // row_ror:8
  DPPMAX(0x142)  // row_bcast15
  DPPMAX(0x143)  // row_bcast31 -> lane 63 holds wave max
  return __int_as_float(__builtin_amdgcn_readlane(__float_as_int(x), 63));
}

__device__ __forceinline__ float rdlane(float v, int lane) {
  return __int_as_float(__builtin_amdgcn_readlane(__float_as_int(v), lane));
}

// One Viterbi step. Exact arithmetic: scores rnd(fv_i + T[i][j]); selection strict->
// ascending index == np.argmax first-index rule; candidate set provably supersets
// column winners (margin Dspan + 0.01 >> fp slack).
// k==1 (81%): sole candidate == the max lane (max lane always passes threshold),
//   so fv[i0]==M EXACTLY -> fv = featc + (M + T[i0][j]), cv=i0, no bp store.
// k>=2 (19%): 4-candidate tree. NOTE: i0 is the lowest-INDEX candidate, not the
//   max lane, so its score MUST be rdlane(fv,i0)+t0 (round-6 bug: used M+t0).
#define CRF_STEP(T_, FEATC_)                                                     \
  do {                                                                           \
    const float M_ = wave_max64(fv);                                             \
    const float thr_ = M_ - DpE;                                                 \
    const unsigned long long cm_ = __ballot(fv >= thr_);                         \
    const int k_ = __popcll(cm_);                                                \
    const int i0_ = __ffsll((long long)cm_) - 1;                                 \
    unsigned cv_;                                                                \
    if (__builtin_expect(k_ == 1, 1)) {                                          \
      const float trow_ = sT[i0_ * Ln + j];                                      \
      fv = (FEATC_) + (M_ + trow_);                                              \
      cv_ = (unsigned)i0_;                                                       \
    } else {                                                                     \
      const unsigned long long m1_ = cm_ & (cm_ - 1);                            \
      const unsigned long long m2_ = m1_ & (m1_ - 1);                            \
      const unsigned long long m3_ = m2_ & (m2_ - 1);                            \
      const int i1_ = __ffsll((long long)m1_) - 1;                               \
      const int i2_ = (k_ > 2) ? (__ffsll((long long)m2_) - 1) : i1_;            \
      const int i3_ = (k_ > 3) ? (__ffsll((long long)m3_) - 1) : i1_;            \
      const float t0_ = sT[i0_ * Ln + j];                                        \
      const float t1_ = sT[i1_ * Ln + j];                                        \
      const float t2_ = sT[i2_ * Ln + j];                                        \
      const float t3_ = sT[i3_ * Ln + j];                                        \
      const float s0_ = rdlane(fv, i0_) + t0_;                                   \
      const float s1_ = rdlane(fv, i1_) + t1_;                                   \
      const float s2_ = rdlane(fv, i2_) + t2_;                                   \
      const float s3_ = rdlane(fv, i3_) + t3_;                                   \
      const bool tkA_ = s1_ > s0_;                                               \
      const float vA_ = tkA_ ? s1_ : s0_;                                        \
      const int xA_ = tkA_ ? i1_ : i0_;                                          \
      const bool tkB_ = s3_ > s2_;                                               \
      const float vB_ = tkB_ ? s3_ : s2_;                                        \
      const int xB_ = tkB_ ? i3_ : i2_;                                          \
      const bool okB_ = (k_ > 2);                                                \
      const bool tkF_ = okB_ && (vB_ > vA_);                                     \
      float best_ = tkF_ ? vB_ : vA_;                                            \
      int bx_ = tkF_ ? xB_ : xA_;                                                \
      if (__builtin_expect(k_ > 4, 0)) {                                         \
        unsigned long long m_ = m3_ & (m3_ - 1);                                 \
        while (m_) {                                                             \
          const int i_ = __ffsll((long long)m_) - 1;                             \
          m_ &= m_ - 1;                                                          \
          const float s_ = rdlane(fv, i_) + sT[i_ * Ln + j];                     \
          const bool tk_ = s_ > best_;                                           \
          best_ = tk_ ? s_ : best_;                                              \
          bx_ = tk_ ? i_ : bx_;                                                  \
        }                                                                        \
      }                                                                          \
      fv = (FEATC_) + best_;                                                     \
      bpb[(size_t)((T_) - 1) * Ln] = (unsigned char)bx_;                         \
      cv_ = 0xFFu;                                                               \
    }                                                                            \
    cw = cw | (cv_ << (8 * ((T_) & 3)));                                         \
    if (((T_) & 3) == 3) {                                                       \
      if (j == 0) coalw[(T_) >> 2] = cw;                                         \
      cw = 0;                                                                    \
    }                                                                            \
  } while (0)

__global__ __launch_bounds__(64) void crf_forward(
    const float* __restrict__ feat,       // [B][S][L]
    const float* __restrict__ Tm,         // [L][L]
    unsigned char* __restrict__ bp,       // [B][S-1][L] backpointers (k>=2 steps only)
    unsigned* __restrict__ coal,          // [B][S/4 words]: per-step istar or 0xFF bytes
    int* __restrict__ last_tag)           // [B]
{
  const int b = blockIdx.x;
  const int j = threadIdx.x;  // tag index 0..63

  __shared__ __align__(16) float sT[Ln * Ln];  // transitions row-major

  // stage T, tracking global span
  float tmx = -1e30f, tmn = 1e30f;
#pragma unroll 8
  for (int i = 0; i < Ln; ++i) {
    const float v = Tm[i * Ln + j];
    sT[i * Ln + j] = v;
    tmx = fmaxf(tmx, v);
    tmn = fminf(tmn, v);
  }
  __syncthreads();
#pragma unroll
  for (int off = 32; off >= 1; off >>= 1) {
    tmx = fmaxf(tmx, __shfl_xor(tmx, off));
    tmn = fminf(tmn, __shfl_xor(tmn, off));
  }
  // fixed margin: Dspan + 0.01 covers all fp rounding (|fv| <= ~6e3 -> 2ulp ~ 1e-3)
  const float DpE = (tmx - tmn) + 0.01f;

  const float* fb = feat + ((size_t)b * Sn) * Ln + j;
  unsigned char* bpb = bp + ((size_t)b * (Sn - 1)) * Ln + j;
  unsigned* coalw = coal + (size_t)b * (Sn / 4);

  unsigned cw = 0;

  // forward_var = features[b][0][:]; 8-deep software prefetch ring (static indices)
  float fv = fb[0];
  float pf[8];
#pragma unroll
  for (int u = 0; u < 8; ++u) pf[u] = fb[(size_t)(1 + u) * Ln];

  // ---- phase 1: t = 1 .. 1008 (126 blocks of 8); prefetch t+8 <= 1016, no clamp ----
  for (int tb = 1; tb <= Sn - 16; tb += 8) {
#pragma unroll
    for (int u = 0; u < 8; ++u) {
      const int t = tb + u;
      const float featc = pf[u];
      pf[u] = fb[(size_t)(t + 8) * Ln];
      CRF_STEP(t, featc);
    }
  }
  // After phase 1: pf[u] = feature[1009 + u].

  // ---- phase 2: t = 1009 .. 1016; refill pf[0..6] with features 1017..1023 ----
#pragma unroll
  for (int u = 0; u < 8; ++u) {
    const int t = 1009 + u;
    const float featc = pf[u];
    if (u < 7) pf[u] = fb[(size_t)(1017 + u) * Ln];
    CRF_STEP(t, featc);
  }

  // ---- phase 3: t = 1017 .. 1023 ----
#pragma unroll
  for (int u = 0; u < 7; ++u) {
    const int t = 1017 + u;
    const float featc = pf[u];
    CRF_STEP(t, featc);
  }

  // last_tag = first-index argmax of final forward_var
  const float Mf = wave_max64(fv);
  const unsigned long long mk = __ballot(fv == Mf);
  if (j == 0) last_tag[b] = __ffsll((long long)mk) - 1;
}

__global__ __launch_bounds__(256) void crf_backtrace(
    const unsigned char* __restrict__ bp, const unsigned char* __restrict__ coal,
    const int* __restrict__ last_tag, int* __restrict__ out)
{
  const int gid = blockIdx.x * blockDim.x + threadIdx.x;
  if (gid >= Bn * Sn) return;
  const int b = gid >> 10;       // / Sn
  const int t = gid & (Sn - 1);  // % Sn

  const unsigned char* cb = coal + (size_t)b * Sn;
  int tag = -1;
  int u = t;
  // walk forward to the nearest chain break (coalesced k==1 step or sequence end)
  while (u < Sn - 1) {
    const unsigned char c = cb[u + 1];
    if (c != 0xFF) { tag = c; break; }  // path[u] = istar of step u+1
    ++u;
  }
  if (u == Sn - 1) tag = last_tag[b];
  // walk back through non-coalesced steps applying stored backpointers
  const unsigned char* bpb = bp + (size_t)b * (Sn - 1) * Ln;
  for (; u > t; --u) tag = bpb[(size_t)(u - 1) * Ln + tag];
  out[gid] = tag;
}

extern "C" void kernel_launch(void* const* d_in, const int* in_sizes, int n_in,
                              void* d_out, int out_size, void* d_ws, size_t ws_size,
                              hipStream_t stream) {
  const float* feat = (const float*)d_in[0];
  const float* Tm = (const float*)d_in[1];

  // workspace layout: bp | coal | last_tag   (~34 MB total)
  unsigned char* bp = (unsigned char*)d_ws;
  const size_t bp_sz = (size_t)Bn * (Sn - 1) * Ln;  // 33,521,664 (word-aligned)
  unsigned char* coal = bp + bp_sz;
  const size_t coal_sz = (size_t)Bn * Sn;           // 524,288
  int* last_tag = (int*)(coal + coal_sz);

  int* out = (int*)d_out;

  crf_forward<<<Bn, 64, 0, stream>>>(feat, Tm, bp, (unsigned*)coal, last_tag);
  const int total = Bn * Sn;
  crf_backtrace<<<(total + 255) / 256, 256, 0, stream>>>(bp, coal, last_tag, out);
}